// Round 2
// 184.043 us; speedup vs baseline: 1.0470x; 1.0470x over previous
//
#include <hip/hip_runtime.h>

#define HWSZ (512 * 512)          // H*W
#define NPIX (8 * HWSZ)           // B*H*W = 2,097,152
#define NBLK 2048                 // NPIX / 4 px-per-thread / 256 thr-per-block
#define LOG32 3.4657359027997265f // log(8) + log(4)

// Raw ext-vector types so __builtin_nontemporal_load works (HIP's float4 is a
// class wrapper and is rejected by the builtin; clang's builtin accepts
// scalar + ext_vector types and lowers to global_load_dwordx4 ... nt).
typedef float f4 __attribute__((ext_vector_type(4)));
typedef int   i4 __attribute__((ext_vector_type(4)));

// Streaming formulation (no max-subtraction: logits ~ N(0,1), exp safe in
// fp32). Per pixel with target t:
//   loss_pix = 3*log(Z) - log(E0) - log(E1) - l_t + log(32)
// Z = sum exp(l_c), E0 = t's half-sum (8ch), E1 = t's quarter-sum (4ch).
//
// R3/R4: logits/target are read exactly once per launch and the harness's
// 512MiB poison fills evict everything between launches, so cache allocation
// is pure overhead -> non-temporal (nt, evict-first) loads on both input
// streams. Partial stores stay plain so the reduce kernel hits L2.
// (R4 = R3 resubmitted verbatim; R3 bench failed at container acquire.)
__global__ __launch_bounds__(256) void hier_loss_main(
    const float* __restrict__ logits,
    const int* __restrict__ target,
    float* __restrict__ partial)
{
    const int tid = blockIdx.x * blockDim.x + threadIdx.x;
    const long p0 = (long)tid * 4;          // 4 consecutive pixels per thread
    const int b  = (int)(p0 >> 18);         // HWSZ = 2^18
    const int hw = (int)(p0 & (HWSZ - 1));  // never crosses batch boundary
    const float* base = logits + (long)b * 16 * HWSZ + hw;

    const i4 t4 = __builtin_nontemporal_load((const i4*)(target + p0));

    f4 q0 = {0, 0, 0, 0}, q1 = {0, 0, 0, 0};
    f4 q2 = {0, 0, 0, 0}, q3 = {0, 0, 0, 0};
    f4 lt = {0, 0, 0, 0};

#define DO_CH(c, qacc)                                                     \
    {                                                                      \
        const f4 v = __builtin_nontemporal_load(                           \
            (const f4*)(base + (long)(c) * HWSZ));                         \
        lt.x = (t4.x == (c)) ? v.x : lt.x;                                 \
        lt.y = (t4.y == (c)) ? v.y : lt.y;                                 \
        lt.z = (t4.z == (c)) ? v.z : lt.z;                                 \
        lt.w = (t4.w == (c)) ? v.w : lt.w;                                 \
        qacc.x += __expf(v.x);                                             \
        qacc.y += __expf(v.y);                                             \
        qacc.z += __expf(v.z);                                             \
        qacc.w += __expf(v.w);                                             \
    }

    DO_CH(0, q0)  DO_CH(1, q0)  DO_CH(2, q0)  DO_CH(3, q0)
    DO_CH(4, q1)  DO_CH(5, q1)  DO_CH(6, q1)  DO_CH(7, q1)
    DO_CH(8, q2)  DO_CH(9, q2)  DO_CH(10, q2) DO_CH(11, q2)
    DO_CH(12, q3) DO_CH(13, q3) DO_CH(14, q3) DO_CH(15, q3)
#undef DO_CH

    float acc = 0.0f;
#define PIX(comp, t)                                                         \
    {                                                                        \
        const float a0 = q0.comp, a1 = q1.comp, a2 = q2.comp, a3 = q3.comp;  \
        const float hA = a0 + a1, hB = a2 + a3;                              \
        const float Z  = hA + hB;                                            \
        const float E0 = ((t) & 8) ? hB : hA;                                \
        const float ea = ((t) & 4) ? a1 : a0;                                \
        const float eb = ((t) & 4) ? a3 : a2;                                \
        const float E1 = ((t) & 8) ? eb : ea;                                \
        acc += 3.0f * __logf(Z) - __logf(E0) - __logf(E1) - lt.comp + LOG32; \
    }
    PIX(x, t4.x) PIX(y, t4.y) PIX(z, t4.z) PIX(w, t4.w)
#undef PIX

    // wave (64-lane) shuffle reduce -> LDS -> one plain store per block
    const int lane = threadIdx.x & 63;
    const int wave = threadIdx.x >> 6;
#pragma unroll
    for (int off = 32; off > 0; off >>= 1)
        acc += __shfl_down(acc, off, 64);

    __shared__ float red[4];
    if (lane == 0) red[wave] = acc;
    __syncthreads();
    if (threadIdx.x == 0)
        partial[blockIdx.x] = (red[0] + red[1]) + (red[2] + red[3]);
}

// Single-block final reduce: 2048 partials -> scalar. Plain store to d_out,
// so no zero-init / memset needed anywhere. float4 loads (2 per thread).
__global__ __launch_bounds__(256) void hier_loss_reduce(
    const float* __restrict__ partial,
    float* __restrict__ out)
{
    const f4 a = *(const f4*)(partial + (long)threadIdx.x * 4);
    const f4 b = *(const f4*)(partial + 1024 + (long)threadIdx.x * 4);
    float s = ((a.x + a.y) + (a.z + a.w)) + ((b.x + b.y) + (b.z + b.w));

    const int lane = threadIdx.x & 63;
    const int wave = threadIdx.x >> 6;
#pragma unroll
    for (int off = 32; off > 0; off >>= 1)
        s += __shfl_down(s, off, 64);

    __shared__ float red[4];
    if (lane == 0) red[wave] = s;
    __syncthreads();
    if (threadIdx.x == 0)
        out[0] = ((red[0] + red[1]) + (red[2] + red[3])) * (1.0f / (float)NPIX);
}

extern "C" void kernel_launch(void* const* d_in, const int* in_sizes, int n_in,
                              void* d_out, int out_size, void* d_ws, size_t ws_size,
                              hipStream_t stream) {
    const float* logits = (const float*)d_in[0];
    const int*   target = (const int*)d_in[1];
    float* out     = (float*)d_out;
    float* partial = (float*)d_ws;   // 2048 floats, fully overwritten each call

    hier_loss_main<<<NBLK, 256, 0, stream>>>(logits, target, partial);
    hier_loss_reduce<<<1, 256, 0, stream>>>(partial, out);
}